// Round 1
// baseline (503.115 us; speedup 1.0000x reference)
//
#include <hip/hip_runtime.h>

typedef unsigned short u16;
typedef __bf16 bf16x8 __attribute__((ext_vector_type(8)));
typedef float f32x4 __attribute__((ext_vector_type(4)));

#define N_TOK 4096
#define DMODEL 1024
#define NH 16
#define DKH 64

__device__ inline u16 f2bf(float f){
  unsigned u = __float_as_uint(f);
  u += 0x7fffu + ((u >> 16) & 1u);
  return (u16)(u >> 16);
}

// ---------- convert X (f32 -> bf16), vectorized ----------
__global__ __launch_bounds__(256) void k_convX(const float* __restrict__ X, u16* __restrict__ Xb){
  int i = blockIdx.x*256 + threadIdx.x;          // one float4 per thread
  const float4 v = reinterpret_cast<const float4*>(X)[i];
  ushort4 o; o.x=f2bf(v.x); o.y=f2bf(v.y); o.z=f2bf(v.z); o.w=f2bf(v.w);
  reinterpret_cast<ushort4*>(Xb)[i] = o;
}

// ---------- transpose+convert W [1024][2048] f32 -> Wt [2048][1024] bf16 ----------
__global__ __launch_bounds__(256) void k_convW(const float* __restrict__ W, u16* __restrict__ Wt){
  __shared__ float tile[64][65];
  const int bn = blockIdx.x*64;   // n (2048)
  const int bk = blockIdx.y*64;   // k (1024)
  const int t = threadIdx.x;
  const int c4 = (t & 15)*4;
  const int r  = t >> 4;
  #pragma unroll
  for (int i=0;i<4;i++){
    int k = r + i*16;
    const float4 v = *reinterpret_cast<const float4*>(&W[(size_t)(bk+k)*2048 + bn + c4]);
    tile[k][c4+0]=v.x; tile[k][c4+1]=v.y; tile[k][c4+2]=v.z; tile[k][c4+3]=v.w;
  }
  __syncthreads();
  #pragma unroll
  for (int i=0;i<4;i++){
    int n = r + i*16;
    ushort4 o;
    o.x = f2bf(tile[c4+0][n]);
    o.y = f2bf(tile[c4+1][n]);
    o.z = f2bf(tile[c4+2][n]);
    o.w = f2bf(tile[c4+3][n]);
    *reinterpret_cast<ushort4*>(&Wt[(size_t)(bn+n)*1024 + bk + c4]) = o;
  }
}

// ---------- GEMM: C[4096][2048] = Xb @ Wt^T (both K-contiguous), scatter to QK / Vt ----------
// QK layout: [h][n][d]  (bf16)   Vt layout: [h][d][n]  (bf16)
__global__ __launch_bounds__(256) void k_gemm(const u16* __restrict__ A, const u16* __restrict__ B,
                                              u16* __restrict__ qk, u16* __restrict__ vt){
  __shared__ alignas(16) u16 As[128*32];   // [128 rows][32 k]
  __shared__ alignas(16) u16 Bs[128*32];   // [128 cols][32 k]
  const int bm = blockIdx.y*128, bn = blockIdx.x*128;
  const int tid = threadIdx.x, wid = tid>>6, lane = tid&63;
  const int wr = wid>>1, wc = wid&1;
  const int lr = lane&15, lg = lane>>4;
  f32x4 acc[4][4] = {};

  for (int kk=0; kk<DMODEL; kk+=32){
    __syncthreads();
    #pragma unroll
    for (int i=0;i<2;i++){
      int chunk = (wid*2+i)*64 + lane;       // 0..511, 16B each
      int row = chunk>>2, ko = (chunk&3)*8;
      const u16* ga = A + (size_t)(bm+row)*DMODEL + kk + ko;
      const u16* gb = B + (size_t)(bn+row)*DMODEL + kk + ko;
      __builtin_amdgcn_global_load_lds((const __attribute__((address_space(1))) void*)ga,
          (__attribute__((address_space(3))) void*)(&As[(wid*2+i)*512]), 16, 0, 0);
      __builtin_amdgcn_global_load_lds((const __attribute__((address_space(1))) void*)gb,
          (__attribute__((address_space(3))) void*)(&Bs[(wid*2+i)*512]), 16, 0, 0);
    }
    asm volatile("s_waitcnt vmcnt(0)" ::: "memory");
    __syncthreads();
    bf16x8 af[4], bfr[4];
    #pragma unroll
    for (int m=0;m<4;m++)
      af[m] = *reinterpret_cast<const bf16x8*>(&As[(wr*64+m*16+lr)*32 + lg*8]);
    #pragma unroll
    for (int n=0;n<4;n++)
      bfr[n] = *reinterpret_cast<const bf16x8*>(&Bs[(wc*64+n*16+lr)*32 + lg*8]);
    #pragma unroll
    for (int m=0;m<4;m++)
      #pragma unroll
      for (int n=0;n<4;n++)
        acc[m][n] = __builtin_amdgcn_mfma_f32_16x16x32_bf16(af[m], bfr[n], acc[m][n], 0,0,0);
  }

  #pragma unroll
  for (int m=0;m<4;m++){
    #pragma unroll
    for (int n=0;n<4;n++){
      const int c = bn + wc*64 + n*16 + lr;
      #pragma unroll
      for (int r=0;r<4;r++){
        const int row = bm + wr*64 + m*16 + lg*4 + r;
        const u16 val = f2bf(acc[m][n][r]);
        if (c < DMODEL){
          const int hh = c>>6, d = c&63;
          qk[((size_t)hh*N_TOK + row)*DKH + d] = val;
        } else {
          const int c2 = c - DMODEL; const int hh = c2>>6, d = c2&63;
          vt[((size_t)hh*DKH + d)*N_TOK + row] = val;
        }
      }
    }
  }
}

// ---------- flash attention: per block = 1 head x 64 q-rows (4 waves x 16 rows) ----------
__global__ __launch_bounds__(256) void k_attn(const u16* __restrict__ qk, const u16* __restrict__ vt,
                                              float* __restrict__ out){
  __shared__ alignas(16) u16 P[4][16*72];   // per-wave P tile, padded (72) to dodge bank conflicts
  const int h   = blockIdx.y;
  const int wid = threadIdx.x>>6;
  const int lane= threadIdx.x & 63;
  const int lr  = lane & 15, lg = lane >> 4;
  const int q0  = blockIdx.x*64 + wid*16;
  const u16* Kh = qk + (size_t)h*N_TOK*DKH;
  const u16* Vh = vt + (size_t)h*DKH*N_TOK;

  bf16x8 qf[2];
  #pragma unroll
  for (int s=0;s<2;s++)
    qf[s] = *reinterpret_cast<const bf16x8*>(&Kh[(size_t)(q0+lr)*DKH + s*32 + lg*8]);

  f32x4 o[4] = {};
  float m2[4], l2[4];
  #pragma unroll
  for (int r=0;r<4;r++){ m2[r] = -1e30f; l2[r] = 0.f; }
  const float SC = 0.125f * 1.44269504088896340736f;   // 1/sqrt(64) * log2(e)

  for (int kt=0; kt<N_TOK; kt+=64){
    f32x4 s[4] = {};
    #pragma unroll
    for (int c=0;c<4;c++){
      #pragma unroll
      for (int ks=0;ks<2;ks++){
        bf16x8 kf = *reinterpret_cast<const bf16x8*>(&Kh[(size_t)(kt + c*16 + lr)*DKH + ks*32 + lg*8]);
        s[c] = __builtin_amdgcn_mfma_f32_16x16x32_bf16(qf[ks], kf, s[c], 0,0,0);
      }
    }
    float mt[4];
    #pragma unroll
    for (int r=0;r<4;r++){
      s[0][r]*=SC; s[1][r]*=SC; s[2][r]*=SC; s[3][r]*=SC;
      mt[r] = fmaxf(fmaxf(s[0][r],s[1][r]), fmaxf(s[2][r],s[3][r]));
    }
    #pragma unroll
    for (int msk=1; msk<16; msk<<=1)
      #pragma unroll
      for (int r=0;r<4;r++) mt[r] = fmaxf(mt[r], __shfl_xor(mt[r], msk, 64));
    float alpha[4], rs[4];
    #pragma unroll
    for (int r=0;r<4;r++){
      float mn = fmaxf(m2[r], mt[r]);
      alpha[r] = exp2f(m2[r] - mn);
      m2[r] = mn;
      rs[r] = 0.f;
    }
    #pragma unroll
    for (int c=0;c<4;c++){
      #pragma unroll
      for (int r=0;r<4;r++){
        float p = exp2f(s[c][r] - m2[r]);
        rs[r] += p;
        P[wid][(lg*4+r)*72 + c*16 + lr] = f2bf(p);
      }
    }
    #pragma unroll
    for (int msk=1; msk<16; msk<<=1)
      #pragma unroll
      for (int r=0;r<4;r++) rs[r] += __shfl_xor(rs[r], msk, 64);
    #pragma unroll
    for (int r=0;r<4;r++) l2[r] = l2[r]*alpha[r] + rs[r];
    #pragma unroll
    for (int f=0;f<4;f++)
      #pragma unroll
      for (int r=0;r<4;r++) o[f][r] *= alpha[r];

    bf16x8 pa[2];
    #pragma unroll
    for (int ks=0;ks<2;ks++)
      pa[ks] = *reinterpret_cast<const bf16x8*>(&P[wid][lr*72 + ks*32 + lg*8]);
    #pragma unroll
    for (int df=0; df<4; df++){
      #pragma unroll
      for (int ks=0;ks<2;ks++){
        bf16x8 vf = *reinterpret_cast<const bf16x8*>(&Vh[(size_t)(df*16+lr)*N_TOK + kt + ks*32 + lg*8]);
        o[df] = __builtin_amdgcn_mfma_f32_16x16x32_bf16(pa[ks], vf, o[df], 0,0,0);
      }
    }
  }
  #pragma unroll
  for (int df=0; df<4; df++)
    #pragma unroll
    for (int r=0;r<4;r++)
      out[(size_t)(q0 + lg*4 + r)*DMODEL + h*DKH + df*16 + lr] = o[df][r] / l2[r];
}

extern "C" void kernel_launch(void* const* d_in, const int* in_sizes, int n_in,
                              void* d_out, int out_size, void* d_ws, size_t ws_size,
                              hipStream_t stream) {
  const float* X = (const float*)d_in[0];
  const float* W = (const float*)d_in[1];
  float* out = (float*)d_out;
  u16* Xb = (u16*)d_ws;                         //  8 MB: [4096][1024]
  u16* Wt = Xb + (size_t)N_TOK*DMODEL;          //  4 MB: [2048][1024]
  u16* QK = Wt + (size_t)2*DMODEL*DMODEL;       //  8 MB: [16][4096][64]
  u16* Vt = QK + (size_t)N_TOK*DMODEL;          //  8 MB: [16][64][4096]

  k_convX<<<dim3(4096), dim3(256), 0, stream>>>(X, Xb);
  k_convW<<<dim3(32,16), dim3(256), 0, stream>>>(W, Wt);
  k_gemm <<<dim3(16,32), dim3(256), 0, stream>>>(Xb, Wt, QK, Vt);
  k_attn <<<dim3(64,16), dim3(256), 0, stream>>>(QK, Vt, out);
}

// Round 2
// 279.880 us; speedup vs baseline: 1.7976x; 1.7976x over previous
//
#include <hip/hip_runtime.h>

typedef unsigned short u16;
typedef unsigned int u32;
typedef __bf16 bf16x8 __attribute__((ext_vector_type(8)));
typedef float f32x4 __attribute__((ext_vector_type(4)));
typedef float f32x16 __attribute__((ext_vector_type(16)));
typedef int i32x2 __attribute__((ext_vector_type(2)));
typedef unsigned int u32x4 __attribute__((ext_vector_type(4)));

#define N_TOK 4096
#define DMODEL 1024
#define NH 16
#define DKH 64

__device__ inline u16 f2bf(float f){
  unsigned u = __float_as_uint(f);
  u += 0x7fffu + ((u >> 16) & 1u);
  return (u16)(u >> 16);
}

// ---------- convert X (f32 -> bf16), vectorized ----------
__global__ __launch_bounds__(256) void k_convX(const float* __restrict__ X, u16* __restrict__ Xb){
  int i = blockIdx.x*256 + threadIdx.x;          // one float4 per thread
  const float4 v = reinterpret_cast<const float4*>(X)[i];
  ushort4 o; o.x=f2bf(v.x); o.y=f2bf(v.y); o.z=f2bf(v.z); o.w=f2bf(v.w);
  reinterpret_cast<ushort4*>(Xb)[i] = o;
}

// ---------- transpose+convert W [1024][2048] f32 -> Wt [2048][1024] bf16 ----------
__global__ __launch_bounds__(256) void k_convW(const float* __restrict__ W, u16* __restrict__ Wt){
  __shared__ float tile[64][65];
  const int bn = blockIdx.x*64;   // n (2048)
  const int bk = blockIdx.y*64;   // k (1024)
  const int t = threadIdx.x;
  const int c4 = (t & 15)*4;
  const int r  = t >> 4;
  #pragma unroll
  for (int i=0;i<4;i++){
    int k = r + i*16;
    const float4 v = *reinterpret_cast<const float4*>(&W[(size_t)(bk+k)*2048 + bn + c4]);
    tile[k][c4+0]=v.x; tile[k][c4+1]=v.y; tile[k][c4+2]=v.z; tile[k][c4+3]=v.w;
  }
  __syncthreads();
  #pragma unroll
  for (int i=0;i<4;i++){
    int n = r + i*16;
    ushort4 o;
    o.x = f2bf(tile[c4+0][n]);
    o.y = f2bf(tile[c4+1][n]);
    o.z = f2bf(tile[c4+2][n]);
    o.w = f2bf(tile[c4+3][n]);
    *reinterpret_cast<ushort4*>(&Wt[(size_t)(bn+n)*1024 + bk + c4]) = o;
  }
}

// ---------- GEMM: C[4096][2048] = Xb @ Wt^T (both K-contiguous), scatter to QK / Vt ----------
// QK layout: [h][n][d]  (bf16)   Vt layout: [h][d][n]  (bf16)
__global__ __launch_bounds__(256) void k_gemm(const u16* __restrict__ A, const u16* __restrict__ B,
                                              u16* __restrict__ qk, u16* __restrict__ vt){
  __shared__ alignas(16) u16 As[128*32];   // [128 rows][32 k]
  __shared__ alignas(16) u16 Bs[128*32];   // [128 cols][32 k]
  const int bm = blockIdx.y*128, bn = blockIdx.x*128;
  const int tid = threadIdx.x, wid = tid>>6, lane = tid&63;
  const int wr = wid>>1, wc = wid&1;
  const int lr = lane&15, lg = lane>>4;
  f32x4 acc[4][4] = {};

  for (int kk=0; kk<DMODEL; kk+=32){
    __syncthreads();
    #pragma unroll
    for (int i=0;i<2;i++){
      int chunk = (wid*2+i)*64 + lane;       // 0..511, 16B each
      int row = chunk>>2, ko = (chunk&3)*8;
      const u16* ga = A + (size_t)(bm+row)*DMODEL + kk + ko;
      const u16* gb = B + (size_t)(bn+row)*DMODEL + kk + ko;
      __builtin_amdgcn_global_load_lds((const __attribute__((address_space(1))) void*)ga,
          (__attribute__((address_space(3))) void*)(&As[(wid*2+i)*512]), 16, 0, 0);
      __builtin_amdgcn_global_load_lds((const __attribute__((address_space(1))) void*)gb,
          (__attribute__((address_space(3))) void*)(&Bs[(wid*2+i)*512]), 16, 0, 0);
    }
    asm volatile("s_waitcnt vmcnt(0)" ::: "memory");
    __syncthreads();
    bf16x8 af[4], bfr[4];
    #pragma unroll
    for (int m=0;m<4;m++)
      af[m] = *reinterpret_cast<const bf16x8*>(&As[(wr*64+m*16+lr)*32 + lg*8]);
    #pragma unroll
    for (int n=0;n<4;n++)
      bfr[n] = *reinterpret_cast<const bf16x8*>(&Bs[(wc*64+n*16+lr)*32 + lg*8]);
    #pragma unroll
    for (int m=0;m<4;m++)
      #pragma unroll
      for (int n=0;n<4;n++)
        acc[m][n] = __builtin_amdgcn_mfma_f32_16x16x32_bf16(af[m], bfr[n], acc[m][n], 0,0,0);
  }

  #pragma unroll
  for (int m=0;m<4;m++){
    #pragma unroll
    for (int n=0;n<4;n++){
      const int c = bn + wc*64 + n*16 + lr;
      #pragma unroll
      for (int r=0;r<4;r++){
        const int row = bm + wr*64 + m*16 + lg*4 + r;
        const u16 val = f2bf(acc[m][n][r]);
        if (c < DMODEL){
          const int hh = c>>6, d = c&63;
          qk[((size_t)hh*N_TOK + row)*DKH + d] = val;
        } else {
          const int c2 = c - DMODEL; const int hh = c2>>6, d = c2&63;
          vt[((size_t)hh*DKH + d)*N_TOK + row] = val;
        }
      }
    }
  }
}

// ---------- flash attention v2: 1 wave = 32 q-rows, swapped 32x32 MFMA, in-register softmax ----------
// P tile via mfma(K,Q): lane holds P[k=crow(c,hi)+32s][q=lane&31] in p0/p1 (f32x16 each).
// crow(c,hi) = (c&3) + 8*(c>>2) + 4*hi.
// PV via mfma(V^T, P): O^T accumulated with col=lane&31=q -> alpha rescale is lane-scalar.
__global__ __launch_bounds__(256,2) void k_attn(const u16* __restrict__ qk, const u16* __restrict__ vt,
                                                float* __restrict__ out){
  const int h    = blockIdx.y;
  const int wid  = threadIdx.x >> 6;
  const int lane = threadIdx.x & 63;
  const int ql   = lane & 31;
  const int hi   = lane >> 5;
  const int q0   = (blockIdx.x*4 + wid)*32;
  const u16* __restrict__ Kh = qk + (size_t)h*N_TOK*DKH;
  const u16* __restrict__ Vh = vt + (size_t)h*DKH*N_TOK;

  // Q as B-fragments: qb[ds][j] = Q[q0+ql][ds*16 + hi*8 + j]
  bf16x8 qb[4];
  #pragma unroll
  for (int ds=0; ds<4; ds++)
    qb[ds] = *reinterpret_cast<const bf16x8*>(&Kh[(size_t)(q0+ql)*DKH + ds*16 + hi*8]);

  f32x16 o0 = {}, o1 = {};            // O^T d-tiles [0..31], [32..63]
  float m = -3e38f, l = 0.f;
  const float SC = 0.18033688011112042f;   // log2(e)/sqrt(64)

  for (int kt=0; kt<N_TOK; kt+=64){
    // ---- QK^T (swapped): p{s} over two 32-key subtiles ----
    f32x16 p0 = {}, p1 = {};
    #pragma unroll
    for (int ds=0; ds<4; ds++){
      bf16x8 kf = *reinterpret_cast<const bf16x8*>(&Kh[(size_t)(kt + ql)*DKH + ds*16 + hi*8]);
      p0 = __builtin_amdgcn_mfma_f32_32x32x16_bf16(kf, qb[ds], p0, 0,0,0);
    }
    #pragma unroll
    for (int ds=0; ds<4; ds++){
      bf16x8 kf = *reinterpret_cast<const bf16x8*>(&Kh[(size_t)(kt + 32 + ql)*DKH + ds*16 + hi*8]);
      p1 = __builtin_amdgcn_mfma_f32_32x32x16_bf16(kf, qb[ds], p1, 0,0,0);
    }

    // ---- issue V loads early (independent of softmax) ----
    // vf[dt][t][j] = V[kt + t*16 + hi*8 + j][dt*32 + ql]  (contiguous in Vt)
    bf16x8 vf0[4], vf1[4];
    #pragma unroll
    for (int t=0; t<4; t++){
      vf0[t] = *reinterpret_cast<const bf16x8*>(&Vh[(size_t)(ql)*N_TOK      + kt + t*16 + hi*8]);
      vf1[t] = *reinterpret_cast<const bf16x8*>(&Vh[(size_t)(32+ql)*N_TOK   + kt + t*16 + hi*8]);
    }

    // ---- in-register online softmax (per-lane q) ----
    float mx0 = p0[0], mx1 = p1[0];
    #pragma unroll
    for (int c=1; c<16; c++){ mx0 = fmaxf(mx0, p0[c]); mx1 = fmaxf(mx1, p1[c]); }
    float pm = fmaxf(mx0, mx1);
    pm = fmaxf(pm, __shfl_xor(pm, 32, 64));
    float mn  = fmaxf(m, pm);
    float mnc = mn * SC;
    float alpha = exp2f(fmaf(m, SC, -mnc));
    m = mn;
    float rs = 0.f;
    #pragma unroll
    for (int c=0; c<16; c++){
      p0[c] = exp2f(fmaf(p0[c], SC, -mnc)); rs += p0[c];
      p1[c] = exp2f(fmaf(p1[c], SC, -mnc)); rs += p1[c];
    }
    rs += __shfl_xor(rs, 32, 64);
    l = l*alpha + rs;
    o0 *= alpha; o1 *= alpha;

    // ---- P (f32, C-layout) -> bf16 B-fragments, all in registers ----
    u32 pk0[8], pk1[8];
    #pragma unroll
    for (int c2=0; c2<8; c2++){
      u32 a, b;
      asm("v_cvt_pk_bf16_f32 %0, %1, %2" : "=v"(a) : "v"(p0[2*c2]), "v"(p0[2*c2+1]));
      asm("v_cvt_pk_bf16_f32 %0, %1, %2" : "=v"(b) : "v"(p1[2*c2]), "v"(p1[2*c2+1]));
      pk0[c2] = a; pk1[c2] = b;
    }

    // ---- PV (swapped): o{dt} = mfma(V^T frag, P B-frag) ----
    #pragma unroll
    for (int t=0; t<4; t++){
      const u32* pks = (t>>1) ? pk1 : pk0;
      const int base = 4*(t&1);
      i32x2 r0 = __builtin_amdgcn_permlane32_swap((int)pks[base+0], (int)pks[base+2], false, false);
      i32x2 r1 = __builtin_amdgcn_permlane32_swap((int)pks[base+1], (int)pks[base+3], false, false);
      u32x4 w; w[0] = (u32)r0[0]; w[1] = (u32)r1[0]; w[2] = (u32)r0[1]; w[3] = (u32)r1[1];
      bf16x8 bt = __builtin_bit_cast(bf16x8, w);
      o0 = __builtin_amdgcn_mfma_f32_32x32x16_bf16(vf0[t], bt, o0, 0,0,0);
      o1 = __builtin_amdgcn_mfma_f32_32x32x16_bf16(vf1[t], bt, o1, 0,0,0);
    }
  }

  // ---- epilogue: out[q][h*64 + d] = O^T[d][q] / l ----
  const float inv = 1.f / l;
  float* orow = out + (size_t)(q0 + ql)*DMODEL + h*DKH;
  #pragma unroll
  for (int g=0; g<4; g++){
    float4 s0, s1;
    s0.x = o0[4*g+0]*inv; s0.y = o0[4*g+1]*inv; s0.z = o0[4*g+2]*inv; s0.w = o0[4*g+3]*inv;
    s1.x = o1[4*g+0]*inv; s1.y = o1[4*g+1]*inv; s1.z = o1[4*g+2]*inv; s1.w = o1[4*g+3]*inv;
    *reinterpret_cast<float4*>(&orow[      8*g + 4*hi]) = s0;   // d = 8g+4hi+e
    *reinterpret_cast<float4*>(&orow[32 +  8*g + 4*hi]) = s1;   // d = 32+8g+4hi+e
  }
}

extern "C" void kernel_launch(void* const* d_in, const int* in_sizes, int n_in,
                              void* d_out, int out_size, void* d_ws, size_t ws_size,
                              hipStream_t stream) {
  const float* X = (const float*)d_in[0];
  const float* W = (const float*)d_in[1];
  float* out = (float*)d_out;
  u16* Xb = (u16*)d_ws;                         //  8 MB: [4096][1024]
  u16* Wt = Xb + (size_t)N_TOK*DMODEL;          //  4 MB: [2048][1024]
  u16* QK = Wt + (size_t)2*DMODEL*DMODEL;       //  8 MB: [16][4096][64]
  u16* Vt = QK + (size_t)N_TOK*DMODEL;          //  8 MB: [16][64][4096]

  k_convX<<<dim3(4096), dim3(256), 0, stream>>>(X, Xb);
  k_convW<<<dim3(32,16), dim3(256), 0, stream>>>(W, Wt);
  k_gemm <<<dim3(16,32), dim3(256), 0, stream>>>(Xb, Wt, QK, Vt);
  k_attn <<<dim3(32,16), dim3(256), 0, stream>>>(QK, Vt, out);
}

// Round 3
// 166.139 us; speedup vs baseline: 3.0283x; 1.6846x over previous
//
#include <hip/hip_runtime.h>

typedef unsigned short u16;
typedef unsigned int u32;
typedef __bf16 bf16x8 __attribute__((ext_vector_type(8)));
typedef float f32x4 __attribute__((ext_vector_type(4)));
typedef float f32x16 __attribute__((ext_vector_type(16)));
typedef int i32x2 __attribute__((ext_vector_type(2)));
typedef unsigned int u32x4 __attribute__((ext_vector_type(4)));

#define N_TOK 4096
#define DMODEL 1024
#define NH 16
#define DKH 64

__device__ inline u16 f2bf(float f){
  unsigned u = __float_as_uint(f);
  u += 0x7fffu + ((u >> 16) & 1u);
  return (u16)(u >> 16);
}

// ---------- convert X (f32 -> bf16), vectorized ----------
__global__ __launch_bounds__(256) void k_convX(const float* __restrict__ X, u16* __restrict__ Xb){
  int i = blockIdx.x*256 + threadIdx.x;
  const float4 v = reinterpret_cast<const float4*>(X)[i];
  ushort4 o; o.x=f2bf(v.x); o.y=f2bf(v.y); o.z=f2bf(v.z); o.w=f2bf(v.w);
  reinterpret_cast<ushort4*>(Xb)[i] = o;
}

// ---------- transpose+convert W [1024][2048] f32 -> Wt [2048][1024] bf16 ----------
__global__ __launch_bounds__(256) void k_convW(const float* __restrict__ W, u16* __restrict__ Wt){
  __shared__ float tile[64][65];
  const int bn = blockIdx.x*64;
  const int bk = blockIdx.y*64;
  const int t = threadIdx.x;
  const int c4 = (t & 15)*4;
  const int r  = t >> 4;
  #pragma unroll
  for (int i=0;i<4;i++){
    int k = r + i*16;
    const float4 v = *reinterpret_cast<const float4*>(&W[(size_t)(bk+k)*2048 + bn + c4]);
    tile[k][c4+0]=v.x; tile[k][c4+1]=v.y; tile[k][c4+2]=v.z; tile[k][c4+3]=v.w;
  }
  __syncthreads();
  #pragma unroll
  for (int i=0;i<4;i++){
    int n = r + i*16;
    ushort4 o;
    o.x = f2bf(tile[c4+0][n]);
    o.y = f2bf(tile[c4+1][n]);
    o.z = f2bf(tile[c4+2][n]);
    o.w = f2bf(tile[c4+3][n]);
    *reinterpret_cast<ushort4*>(&Wt[(size_t)(bn+n)*1024 + bk + c4]) = o;
  }
}

// ---------- GEMM: proj[4096][2048] = Xb @ Wt^T, scatter to fragment-major Kf / Vf ----------
// Kf chunk layout: elem(h,kb,ds,l,j) = K[h][kb*32 + (l&31)][ds*16 + (l>>5)*8 + j]
//   u16 idx = (h*512 + kb*4 + ds)*512 + l*8 + j          (per head 262144 u16)
// Vf chunk layout: elem(h,kb,dt,t,l,j) = V[h][dt*32 + (l&31)][kb*64 + t*16 + (l>>5)*8 + j]
//   u16 idx = ((h*64 + kb)*8 + dt*4 + t)*512 + l*8 + j   (per head 262144 u16)
__global__ __launch_bounds__(256) void k_gemm(const u16* __restrict__ A, const u16* __restrict__ B,
                                              u16* __restrict__ kf_g, u16* __restrict__ vf_g){
  __shared__ alignas(16) u16 As[128*32];
  __shared__ alignas(16) u16 Bs[128*32];
  const int bm = blockIdx.y*128, bn = blockIdx.x*128;
  const int tid = threadIdx.x, wid = tid>>6, lane = tid&63;
  const int wr = wid>>1, wc = wid&1;
  const int lr = lane&15, lg = lane>>4;
  f32x4 acc[4][4] = {};

  for (int kk=0; kk<DMODEL; kk+=32){
    __syncthreads();
    #pragma unroll
    for (int i=0;i<2;i++){
      int chunk = (wid*2+i)*64 + lane;
      int row = chunk>>2, ko = (chunk&3)*8;
      const u16* ga = A + (size_t)(bm+row)*DMODEL + kk + ko;
      const u16* gb = B + (size_t)(bn+row)*DMODEL + kk + ko;
      __builtin_amdgcn_global_load_lds((const __attribute__((address_space(1))) void*)ga,
          (__attribute__((address_space(3))) void*)(&As[(wid*2+i)*512]), 16, 0, 0);
      __builtin_amdgcn_global_load_lds((const __attribute__((address_space(1))) void*)gb,
          (__attribute__((address_space(3))) void*)(&Bs[(wid*2+i)*512]), 16, 0, 0);
    }
    asm volatile("s_waitcnt vmcnt(0)" ::: "memory");
    __syncthreads();
    bf16x8 af[4], bfr[4];
    #pragma unroll
    for (int m=0;m<4;m++)
      af[m] = *reinterpret_cast<const bf16x8*>(&As[(wr*64+m*16+lr)*32 + lg*8]);
    #pragma unroll
    for (int n=0;n<4;n++)
      bfr[n] = *reinterpret_cast<const bf16x8*>(&Bs[(wc*64+n*16+lr)*32 + lg*8]);
    #pragma unroll
    for (int m=0;m<4;m++)
      #pragma unroll
      for (int n=0;n<4;n++)
        acc[m][n] = __builtin_amdgcn_mfma_f32_16x16x32_bf16(af[m], bfr[n], acc[m][n], 0,0,0);
  }

  #pragma unroll
  for (int m=0;m<4;m++){
    const int row0 = bm + wr*64 + m*16 + lg*4;
    #pragma unroll
    for (int n=0;n<4;n++){
      const int c = bn + wc*64 + n*16 + lr;
      if (c < DMODEL){
        const int hh = c>>6, d = c&63;
        const size_t base = ((size_t)hh*512 + (size_t)(row0>>5)*4 + (d>>4))*512;
        #pragma unroll
        for (int r=0;r<4;r++){
          const int row = row0 + r;
          kf_g[base + (size_t)(((row&31) | (((d>>3)&1)<<5)))*8 + (d&7)] = f2bf(acc[m][n][r]);
        }
      } else {
        const int cc = c - DMODEL; const int hh = cc>>6, d = cc&63;
        const size_t base = (((size_t)hh*64 + (row0>>6))*8 + (d>>5)*4 + ((row0>>4)&3))*512
                          + (size_t)(((d&31) | (((row0>>3)&1)<<5)))*8 + (row0&7);
        ushort4 o;
        o.x = f2bf(acc[m][n][0]); o.y = f2bf(acc[m][n][1]);
        o.z = f2bf(acc[m][n][2]); o.w = f2bf(acc[m][n][3]);
        *reinterpret_cast<ushort4*>(&vf_g[base]) = o;
      }
    }
  }
}

// ---------- flash attention v3: fragment-major global loads (all base+lane*16B), K prefetch ----------
__global__ __launch_bounds__(256,2) void k_attn(const u16* __restrict__ kf_g, const u16* __restrict__ vf_g,
                                                float* __restrict__ out){
  const int h    = blockIdx.y;
  const int wid  = threadIdx.x >> 6;
  const int lane = threadIdx.x & 63;
  const int ql   = lane & 31;
  const int q0   = (blockIdx.x*4 + wid)*32;
  const u16* __restrict__ Kfh = kf_g + (size_t)h*262144;
  const u16* __restrict__ Vfh = vf_g + (size_t)h*262144;

  // Q as B-fragments (coalesced: base + lane*16B)
  bf16x8 qb[4];
  #pragma unroll
  for (int ds=0; ds<4; ds++)
    qb[ds] = *reinterpret_cast<const bf16x8*>(&Kfh[(size_t)((q0>>5)*4 + ds)*512 + lane*8]);

  f32x16 o0 = {}, o1 = {};
  float m = -3e38f, l = 0.f;
  const float SC = 0.18033688011112042f;   // log2(e)/sqrt(64)

  bf16x8 kfA[8], kfB[8];
  #pragma unroll
  for (int fi=0; fi<8; fi++)
    kfA[fi] = *reinterpret_cast<const bf16x8*>(&Kfh[(size_t)fi*512 + lane*8]);   // tile kt=0

  auto body = [&](bf16x8* kf, int kt){
    // V loads for this tile (independent; consumed after softmax)
    const u16* vb = Vfh + ((size_t)(kt>>6)*8)*512 + lane*8;
    bf16x8 vf0[4], vf1[4];
    #pragma unroll
    for (int t=0; t<4; t++){
      vf0[t] = *reinterpret_cast<const bf16x8*>(vb + (size_t)t*512);
      vf1[t] = *reinterpret_cast<const bf16x8*>(vb + (size_t)(4+t)*512);
    }
    // QK^T (swapped): kf prefetched >1 body ago
    f32x16 p0 = {}, p1 = {};
    #pragma unroll
    for (int ds=0; ds<4; ds++) p0 = __builtin_amdgcn_mfma_f32_32x32x16_bf16(kf[ds],   qb[ds], p0, 0,0,0);
    #pragma unroll
    for (int ds=0; ds<4; ds++) p1 = __builtin_amdgcn_mfma_f32_32x32x16_bf16(kf[4+ds], qb[ds], p1, 0,0,0);

    // tile max (balanced tree, depth ~6)
    float mx[8];
    #pragma unroll
    for (int i=0;i<8;i++) mx[i] = fmaxf(fmaxf(p0[i], p0[i+8]), fmaxf(p1[i], p1[i+8]));
    float a0 = fmaxf(mx[0],mx[1]), a1 = fmaxf(mx[2],mx[3]);
    float a2 = fmaxf(mx[4],mx[5]), a3 = fmaxf(mx[6],mx[7]);
    float pm = fmaxf(fmaxf(a0,a1), fmaxf(a2,a3));
    pm = fmaxf(pm, __shfl_xor(pm, 32, 64));

    // T13 defer-max: skip rescale while tile max grows < 8 raw-score units
    if (!__all(pm <= m + 8.f)){
      float mn = fmaxf(m, pm);
      float alpha = exp2f((m - mn)*SC);
      l *= alpha; o0 *= alpha; o1 *= alpha;
      m = mn;
    }
    const float mnc = m*SC;
    #pragma unroll
    for (int c=0; c<16; c++){
      p0[c] = exp2f(fmaf(p0[c], SC, -mnc));
      p1[c] = exp2f(fmaf(p1[c], SC, -mnc));
    }
    // sum (balanced tree)
    float r0 = ((p0[0]+p0[1])+(p0[2]+p0[3])) + ((p0[4]+p0[5])+(p0[6]+p0[7]));
    float r1 = ((p0[8]+p0[9])+(p0[10]+p0[11])) + ((p0[12]+p0[13])+(p0[14]+p0[15]));
    float r2 = ((p1[0]+p1[1])+(p1[2]+p1[3])) + ((p1[4]+p1[5])+(p1[6]+p1[7]));
    float r3 = ((p1[8]+p1[9])+(p1[10]+p1[11])) + ((p1[12]+p1[13])+(p1[14]+p1[15]));
    float rs = (r0+r1)+(r2+r3);
    rs += __shfl_xor(rs, 32, 64);
    l += rs;

    // P (f32, C-layout) -> bf16 B-fragments in registers
    u32 pk0[8], pk1[8];
    #pragma unroll
    for (int c2=0; c2<8; c2++){
      u32 a, b;
      asm("v_cvt_pk_bf16_f32 %0, %1, %2" : "=v"(a) : "v"(p0[2*c2]), "v"(p0[2*c2+1]));
      asm("v_cvt_pk_bf16_f32 %0, %1, %2" : "=v"(b) : "v"(p1[2*c2]), "v"(p1[2*c2+1]));
      pk0[c2] = a; pk1[c2] = b;
    }
    // PV (swapped)
    #pragma unroll
    for (int t=0; t<4; t++){
      const u32* pks = (t>>1) ? pk1 : pk0;
      const int base = 4*(t&1);
      i32x2 r0s = __builtin_amdgcn_permlane32_swap((int)pks[base+0], (int)pks[base+2], false, false);
      i32x2 r1s = __builtin_amdgcn_permlane32_swap((int)pks[base+1], (int)pks[base+3], false, false);
      u32x4 w; w[0] = (u32)r0s[0]; w[1] = (u32)r1s[0]; w[2] = (u32)r0s[1]; w[3] = (u32)r1s[1];
      bf16x8 bt = __builtin_bit_cast(bf16x8, w);
      o0 = __builtin_amdgcn_mfma_f32_32x32x16_bf16(vf0[t], bt, o0, 0,0,0);
      o1 = __builtin_amdgcn_mfma_f32_32x32x16_bf16(vf1[t], bt, o1, 0,0,0);
    }
  };

  auto loadK = [&](bf16x8* dst, int kt){
    const u16* kb = Kfh + ((size_t)(kt>>5)*4)*512 + lane*8;
    #pragma unroll
    for (int fi=0; fi<8; fi++)
      dst[fi] = *reinterpret_cast<const bf16x8*>(kb + (size_t)fi*512);
  };

  for (int it=0; it<32; ++it){
    const int ktA = it<<7;
    loadK(kfB, ktA+64);            // prefetch tile B (consumed after body A)
    body(kfA, ktA);
    if (it < 31) loadK(kfA, ktA+128);  // prefetch next tile A (consumed after body B)
    body(kfB, ktA+64);
  }

  // epilogue: out[q][h*64 + d] = O^T[d][q] / l
  const int hi = lane >> 5;
  const float inv = 1.f / l;
  float* orow = out + (size_t)(q0 + ql)*DMODEL + h*DKH;
  #pragma unroll
  for (int g=0; g<4; g++){
    float4 s0, s1;
    s0.x = o0[4*g+0]*inv; s0.y = o0[4*g+1]*inv; s0.z = o0[4*g+2]*inv; s0.w = o0[4*g+3]*inv;
    s1.x = o1[4*g+0]*inv; s1.y = o1[4*g+1]*inv; s1.z = o1[4*g+2]*inv; s1.w = o1[4*g+3]*inv;
    *reinterpret_cast<float4*>(&orow[      8*g + 4*hi]) = s0;
    *reinterpret_cast<float4*>(&orow[32 +  8*g + 4*hi]) = s1;
  }
}

extern "C" void kernel_launch(void* const* d_in, const int* in_sizes, int n_in,
                              void* d_out, int out_size, void* d_ws, size_t ws_size,
                              hipStream_t stream) {
  const float* X = (const float*)d_in[0];
  const float* W = (const float*)d_in[1];
  float* out = (float*)d_out;
  u16* Xb = (u16*)d_ws;                         //  8 MB
  u16* Wt = Xb + (size_t)N_TOK*DMODEL;          //  4 MB
  u16* Kf = Wt + (size_t)2*DMODEL*DMODEL;       //  8 MB fragment-major K/Q
  u16* Vf = Kf + (size_t)N_TOK*DMODEL;          //  8 MB fragment-major V^T

  k_convX<<<dim3(4096), dim3(256), 0, stream>>>(X, Xb);
  k_convW<<<dim3(32,16), dim3(256), 0, stream>>>(W, Wt);
  k_gemm <<<dim3(16,32), dim3(256), 0, stream>>>(Xb, Wt, Kf, Vf);
  k_attn <<<dim3(32,16), dim3(256), 0, stream>>>(Kf, Vf, out);
}